// Round 14
// baseline (186.839 us; speedup 1.0000x reference)
//
#include <hip/hip_runtime.h>
#include <math.h>

// Converse2D on gfx950 — spectral restructuring (R16):
//   out(2y+u, 2x+v) plane = ifft136( A_uv[g] * Xhat[g] ), per (n,c,u,v)
//   Xhat = rfft136x136(wrap_pad(x)); A_uv = per-channel multiplier (Hermitian).
// R16 (vs R15): attack occupancy. conv is phase-latency bound and 1 WG/CU
//   (161KB LDS) means no co-resident WG ever hides the ~19 barrier drains.
//   - ONE float2 plane [136][73] = 79,424 B with twiddle tables EMBEDDED in
//     pad columns 69/70/71 (lutI/tI136/tI68; 306 entries <= 544 pad slots)
//     -> 2 WGs/CU; barrier stalls overlap between WGs.
//   - inverse = four single-v iterations (R6's verified float2 path, stride
//     73); store = two scalar writes/item (50% line density, R6-proven).
//   - __launch_bounds__(1024,8) pins VGPR<=64 for 8 waves/SIMD.
//   Tripwires: OccupancyPercent must ~double; WRITE_SIZE jump = spill.

#define MDIM 136
#define RSC2 73             // float2 plane row stride (69 data + 4 pad/table cols)
#define HC   69             // stored Hermitian half columns (0..68)
#define PLANE_HALF (MDIM*HC)   // 9384 per plane
#define NPLANES 256         // N*C
#define LDS_BYTES (MDIM*RSC2*8)   // 79,424 B -> 2 WGs/CU
#define PI_D 3.14159265358979323846
#define NTH 1024

__device__ __forceinline__ int slot136(int k) { return 17*(k & 7) + (k >> 3); }
__device__ __forceinline__ int slot68(int k)  { return 17*(k & 3) + (k >> 2); }

// ---------- twiddle tables embedded in plane pad columns ----------
__device__ __forceinline__ float2 LUTI(const float2* z, int t)  // exp(+2pi i t/136)
{ return z[t*RSC2 + 69]; }
__device__ __forceinline__ float2 T136(const float2* z, int i)  // w136^(k1*n2), inv dir
{ return z[i*RSC2 + 70]; }
__device__ __forceinline__ float2 T68v(const float2* z, int i)  // w68^((j+1)*n2), inv dir
{ return z[i*RSC2 + 71]; }

// ---------- symmetric 17-point DFT (float2), strided, sink outputs ----------
template<int DIR, class F>
__device__ __forceinline__ void dft17_sink(float2* z, int base, int stride, F f)
{
    constexpr float C17[9] = {1.f, 0.93247223f, 0.73900892f, 0.44573836f,
                              0.09226836f, -0.27366299f, -0.60263464f,
                              -0.85021714f, -0.98297310f};
    constexpr float S17[9] = {0.f, 0.36124167f, 0.67369564f, 0.89516329f,
                              0.99573418f, 0.96182564f, 0.79801723f,
                              0.52643216f, 0.18374952f};
    constexpr float d = (DIR > 0) ? 1.f : -1.f;
    float xr[17], xi[17];
#pragma unroll
    for (int n = 0; n < 17; n++) {
        float2 v = z[base + n*stride];
        xr[n] = v.x; xi[n] = v.y;
    }
    float ar[8], ai[8], br[8], bi[8];
#pragma unroll
    for (int n = 1; n <= 8; n++) {
        ar[n-1] = xr[n] + xr[17-n];  ai[n-1] = xi[n] + xi[17-n];
        br[n-1] = xr[n] - xr[17-n];  bi[n-1] = xi[n] - xi[17-n];
    }
    float s0r = xr[0], s0i = xi[0];
#pragma unroll
    for (int n = 0; n < 8; n++) { s0r += ar[n]; s0i += ai[n]; }
    f(0, s0r, s0i);
#pragma unroll
    for (int k = 1; k <= 8; k++) {
        float Pr = xr[0], Pi = xi[0], Qr = 0.f, Qi = 0.f;
#pragma unroll
        for (int n = 1; n <= 8; n++) {
            int m = (k*n) % 17;
            float cc = (m <= 8) ? C17[m] : C17[17-m];
            float ss = (m <= 8) ? S17[m] : -S17[17-m];
            Pr = fmaf(ar[n-1], cc, Pr);
            Pi = fmaf(ai[n-1], cc, Pi);
            Qr = fmaf(br[n-1], ss, Qr);
            Qi = fmaf(bi[n-1], ss, Qi);
        }
        f(k,    Pr - d*Qi, Pi + d*Qr);
        f(17-k, Pr + d*Qi, Pi - d*Qr);
    }
}

// ---------- radix-4 + embedded-table twiddle; writes col-slots 17j + n2 ----------
template<int DIR>
__device__ __forceinline__ void radix4_tw(float2* z, int base, int n2,
                                          float2 Z0, float2 Z1, float2 Z2, float2 Z3)
{
    constexpr float d = (DIR > 0) ? 1.0f : -1.0f;
    float t0r = Z0.x+Z2.x, t0i = Z0.y+Z2.y;
    float t1r = Z0.x-Z2.x, t1i = Z0.y-Z2.y;
    float t2r = Z1.x+Z3.x, t2i = Z1.y+Z3.y;
    float t3r = Z1.x-Z3.x, t3i = Z1.y-Z3.y;
    float X0r = t0r+t2r,     X0i = t0i+t2i;
    float X2r = t0r-t2r,     X2i = t0i-t2i;
    float X1r = t1r - d*t3i, X1i = t1i + d*t3r;
    float X3r = t1r + d*t3i, X3i = t1i - d*t3r;
    z[base + n2] = make_float2(X0r, X0i);
    float2 w1 = T68v(z, n2), w2 = T68v(z, 17 + n2), w3 = T68v(z, 34 + n2);
    if (DIR < 0) { w1.y = -w1.y; w2.y = -w2.y; w3.y = -w3.y; }
    z[base + 17 + n2] = make_float2(X1r*w1.x - X1i*w1.y, X1r*w1.y + X1i*w1.x);
    z[base + 34 + n2] = make_float2(X2r*w2.x - X2i*w2.y, X2r*w2.y + X2i*w2.x);
    z[base + 51 + n2] = make_float2(X3r*w3.x - X3i*w3.y, X3r*w3.y + X3i*w3.x);
}

// ---------- 136-pt CT stage 1 (radix-8 + embedded-table twiddle) ----------
template<int DIR>
__device__ __forceinline__ void fft136_s1_body(float2* z, int c, int n2)
{
    constexpr float d = (DIR > 0) ? 1.0f : -1.0f;
    constexpr float C707 = 0.70710678118654752f;
    float xr[8], xi[8];
#pragma unroll
    for (int n1 = 0; n1 < 8; n1++) {
        float2 v = z[(17*n1 + n2)*RSC2 + c];
        xr[n1] = v.x; xi[n1] = v.y;
    }
    float e0r = xr[0]+xr[4], e0i = xi[0]+xi[4];
    float e1r = xr[0]-xr[4], e1i = xi[0]-xi[4];
    float o0r = xr[2]+xr[6], o0i = xi[2]+xi[6];
    float o1r = xr[2]-xr[6], o1i = xi[2]-xi[6];
    float E0r = e0r+o0r, E0i = e0i+o0i;
    float E2r = e0r-o0r, E2i = e0i-o0i;
    float E1r = e1r - d*o1i, E1i = e1i + d*o1r;
    float E3r = e1r + d*o1i, E3i = e1i - d*o1r;
    float f0r = xr[1]+xr[5], f0i = xi[1]+xi[5];
    float f1r = xr[1]-xr[5], f1i = xi[1]-xi[5];
    float h0r = xr[3]+xr[7], h0i = xi[3]+xi[7];
    float h1r = xr[3]-xr[7], h1i = xi[3]-xi[7];
    float O0r = f0r+h0r, O0i = f0i+h0i;
    float O2r = f0r-h0r, O2i = f0i-h0i;
    float O1r = f1r - d*h1i, O1i = f1i + d*h1r;
    float O3r = f1r + d*h1i, O3i = f1i - d*h1r;
    float t1r =  C707*(O1r - d*O1i), t1i = C707*(O1i + d*O1r);
    float t2r = -d*O2i,              t2i = d*O2r;
    float t3r = -C707*(O3r + d*O3i), t3i = C707*(d*O3r - O3i);
    float Xr[8], Xi[8];
    Xr[0]=E0r+O0r; Xi[0]=E0i+O0i;  Xr[4]=E0r-O0r; Xi[4]=E0i-O0i;
    Xr[1]=E1r+t1r; Xi[1]=E1i+t1i;  Xr[5]=E1r-t1r; Xi[5]=E1i-t1i;
    Xr[2]=E2r+t2r; Xi[2]=E2i+t2i;  Xr[6]=E2r-t2r; Xi[6]=E2i-t2i;
    Xr[3]=E3r+t3r; Xi[3]=E3i+t3i;  Xr[7]=E3r-t3r; Xi[7]=E3i-t3i;
    z[n2*RSC2 + c] = make_float2(Xr[0], Xi[0]);
#pragma unroll
    for (int k1 = 1; k1 < 8; k1++) {
        float2 w = T136(z, (k1-1)*17 + n2);
        if (DIR < 0) w.y = -w.y;
        z[(17*k1 + n2)*RSC2 + c] = make_float2(Xr[k1]*w.x - Xi[k1]*w.y,
                                               Xr[k1]*w.y + Xi[k1]*w.x);
    }
}

// c2r pack: Zf[j] from a=T[j], b=T[68-j], w=lut[j] (+1 dir LUT).
__device__ __forceinline__ float2 c2r_pack(float2 a, float2 b, float2 w)
{
    float Sr = a.x + b.x, Si = a.y - b.y;
    float Dr = a.x - b.x, Di = a.y + b.y;
    float Or = w.x*Dr - w.y*Di, Oi = w.x*Di + w.y*Dr;
    return make_float2(Sr - Oi, Si + Or);
}

// ---------- Fused forward + inverse: one WG per (n,c) plane (256 WGs) ----------
__global__ __launch_bounds__(1024, 8) void conv_kernel(const float* __restrict__ x,
                                                       const float2* __restrict__ Abuf,
                                                       float* __restrict__ out)
{
    extern __shared__ float2 z2[];           // [136][73]: cols 0..68 data, 69..71 tables
    const int tid = threadIdx.x;
    const int nc  = blockIdx.x;              // n*64 + c
    const int c   = nc & 63;

    if (tid < MDIM) {
        float s, cc; sincosf(2.0f*(float)PI_D*(float)tid/136.0f, &s, &cc);
        z2[tid*RSC2 + 69] = make_float2(cc, s);                 // lutI
    } else if (tid < MDIM + 119) {
        int it = tid - MDIM;
        int k1 = it/17 + 1, n2 = it - (it/17)*17;
        float s, cc; sincosf((float)(PI_D/68.0)*(float)(k1*n2), &s, &cc);
        z2[it*RSC2 + 70] = make_float2(cc, s);                  // tI136
    } else if (tid < MDIM + 119 + 51) {
        int it = tid - MDIM - 119;
        int j = it/17, n2 = it - 17*j;
        float s, cc; sincosf((float)(PI_D/34.0)*(float)((j+1)*n2), &s, &cc);
        z2[it*RSC2 + 71] = make_float2(cc, s);                  // tI68
    }
    // ---------------- forward ----------------
    const float* xp = x + (size_t)nc * (128*128);
    {   // packed-row load: z2[i][n] = xp(i,2n) + i*xp(i,2n+1), wrap pad by 4
        int i = tid / 68, n = tid - (tid/68)*68;
        for (int e = tid; e < MDIM*68; e += NTH) {
            int si = (i + 124) & 127;
            int j0 = (2*n + 124) & 127;              // always even, pair never wraps
            z2[i*RSC2 + n] = *reinterpret_cast<const float2*>(xp + si*128 + j0);
            i += 15; n += 4; if (n >= 68) { n -= 68; i++; }
        }
    }
    __syncthreads();
    {   // rows stage 1 (radix-4)
        int row = tid / 17;
        int n2  = tid - row*17;
        for (int e = tid; e < MDIM*17; e += NTH) {
            int base = row*RSC2;
            float2 Z0 = z2[base + n2];
            float2 Z1 = z2[base + 17 + n2];
            float2 Z2 = z2[base + 34 + n2];
            float2 Z3 = z2[base + 51 + n2];
            radix4_tw<-1>(z2, base, n2, Z0, Z1, Z2, Z3);
            row += 60; n2 += 4; if (n2 >= 17) { n2 -= 17; row++; }
        }
    }
    __syncthreads();
    if (tid < MDIM*4) {                              // rows stage 2: Z[k] at slot68(k)
        int row = tid >> 2, k1 = tid & 3;
        int base = row*RSC2 + 17*k1;
        dft17_sink<-1>(z2, base, 1, [&](int k2, float re, float im) {
            z2[base + k2] = make_float2(re, im);
        });
    }
    __syncthreads();
    {   // r2c unpack: item k handles (k, 68-k), in-place at slots
        int row = tid / 35, k = tid - (tid/35)*35;
        for (int e = tid; e < MDIM*35; e += NTH) {
            int base = row*RSC2;
            int sa = slot68(k);
            float2 Za = z2[base+sa];
            float Zar = Za.x, Zai = Za.y;
            float Zbr, Zbi; int sb;
            if (k == 0) { Zbr = Zar; Zbi = Zai; sb = 68; }  // Z[68]==Z[0]; X[68]->col 68
            else {
                int kk = 68-k; sb = slot68(kk);
                float2 Zb = z2[base+sb]; Zbr = Zb.x; Zbi = Zb.y;
            }
            float2 w = LUTI(z2, k);                         // conj -> fwd w136^k
            float wc = w.x, ws = -w.y;
            float Er = 0.5f*(Zar + Zbr), Ei = 0.5f*(Zai - Zbi);
            float Dr = 0.5f*(Zar - Zbr), Di = 0.5f*(Zai + Zbi);
            float Tr = wc*Dr - ws*Di, Ti = wc*Di + ws*Dr;   // w^k * D
            z2[base+sa] = make_float2(Er + Ti, Ei - Tr);    // X[k] = E - i*(w^k D)
            float E2r = Er,  E2i = -Ei;
            float D2r = -Dr, D2i = Di;
            float w2c = -wc, w2s = ws;                      // w136^(68-k) = -conj(w^k)
            float T2r = w2c*D2r - w2s*D2i, T2i = w2c*D2i + w2s*D2r;
            z2[base+sb] = make_float2(E2r + T2i, E2i - T2r); // X[68-k]
            row += 29; k += 9; if (k >= 35) { k -= 35; row++; }
        }
    }
    __syncthreads();
    for (int e = tid; e < HC*17; e += NTH) {         // columns stage 1 (69 cols)
        int cc = (e*241) >> 12;                      // e/17, e <= 1172
        int n2 = e - cc*17;
        fft136_s1_body<-1>(z2, cc, n2);
    }
    __syncthreads();
    if (tid < HC*8) {                                // columns stage 2, in place
        int cc = tid >> 3, k1 = tid & 7;
        int base = 17*k1*RSC2 + cc;
        dft17_sink<-1>(z2, base, RSC2, [&](int k2, float re, float im) {
            z2[base + k2*RSC2] = make_float2(re, im);
        });
    }
    __syncthreads();
    // ---------------- capture Xhat to registers ----------------
    float2 Xreg[10];
    {
        int g1 = tid / HC, g2 = tid - (tid/HC)*HC;
#pragma unroll
        for (int k = 0; k < 10; k++) {
            if (k < 9 || tid < PLANE_HALF - 9*NTH) {     // tail: 168 threads
                int cq = (g2 == 68) ? 68 : slot68(g2);
                Xreg[k] = z2[slot136(g1)*RSC2 + cq];
            }
            g1 += 14; g2 += 58; if (g2 >= HC) { g2 -= HC; g1++; }
        }
    }
    __syncthreads();
    // ---------------- inverse, four (u,v) iterations ----------------
    float* op = out + (size_t)nc * (256*256);
#pragma unroll 1
    for (int uv = 0; uv < 4; uv++) {
        const int u = uv >> 1, v = uv & 1;
        const float2* Ap = Abuf + (size_t)(c*4 + u*2 + v) * PLANE_HALF;
        {   // S = A_uv * Xhat, natural [g1][g2]
            int g1 = tid / HC, g2 = tid - (tid/HC)*HC;
#pragma unroll
            for (int k = 0; k < 10; k++) {
                if (k < 9 || tid < PLANE_HALF - 9*NTH) {
                    float2 xv = Xreg[k];
                    float2 av = Ap[tid + k*NTH];
                    z2[g1*RSC2 + g2] = make_float2(av.x*xv.x - av.y*xv.y,
                                                   av.x*xv.y + av.y*xv.x);
                }
                g1 += 14; g2 += 58; if (g2 >= HC) { g2 -= HC; g1++; }
            }
        }
        __syncthreads();
        for (int e = tid; e < HC*17; e += NTH) {     // columns stage 1
            int cc = (e*241) >> 12;
            int n2 = e - cc*17;
            fft136_s1_body<1>(z2, cc, n2);
        }
        __syncthreads();
        if (tid < HC*8) {                            // columns stage 2 (rows->slot136)
            int cc = tid >> 3, k1 = tid & 7;
            int base = 17*k1*RSC2 + cc;
            dft17_sink<1>(z2, base, RSC2, [&](int k2, float re, float im) {
                z2[base + k2*RSC2] = make_float2(re, im);
            });
        }
        __syncthreads();
        // Fused c2r pack + ct68 stage 1 (rows): 136*9 = 1224 items.
        for (int it = tid; it < MDIM*9; it += NTH) {
            int row = (it*7282) >> 16;                // it/9, it <= 1223
            int g   = it - row*9;
            int base = row*RSC2;
            if (g == 0) {
                float2 T0  = z2[base],    T17 = z2[base+17], T34 = z2[base+34],
                       T51 = z2[base+51], T68 = z2[base+68];
                float2 Z0 = c2r_pack(T0,  T68, LUTI(z2, 0));
                float2 Z1 = c2r_pack(T17, T51, LUTI(z2, 17));
                float2 Z2 = c2r_pack(T34, T34, LUTI(z2, 34));
                float2 Z3 = c2r_pack(T51, T17, LUTI(z2, 51));
                radix4_tw<1>(z2, base, 0, Z0, Z1, Z2, Z3);
            } else {
                int gb = 17 - g;
                float2 Ta0 = z2[base+g],    Ta1 = z2[base+g+17],
                       Ta2 = z2[base+g+34], Ta3 = z2[base+g+51];
                float2 Tb0 = z2[base+gb],    Tb1 = z2[base+gb+17],
                       Tb2 = z2[base+gb+34], Tb3 = z2[base+gb+51];
                // partner of (g+17*n1) is (gb+17*(3-n1)), and vice versa
                float2 Za0 = c2r_pack(Ta0, Tb3, LUTI(z2, g));
                float2 Za1 = c2r_pack(Ta1, Tb2, LUTI(z2, g+17));
                float2 Za2 = c2r_pack(Ta2, Tb1, LUTI(z2, g+34));
                float2 Za3 = c2r_pack(Ta3, Tb0, LUTI(z2, g+51));
                float2 Zb0 = c2r_pack(Tb0, Ta3, LUTI(z2, gb));
                float2 Zb1 = c2r_pack(Tb1, Ta2, LUTI(z2, gb+17));
                float2 Zb2 = c2r_pack(Tb2, Ta1, LUTI(z2, gb+34));
                float2 Zb3 = c2r_pack(Tb3, Ta0, LUTI(z2, gb+51));
                radix4_tw<1>(z2, base, g,  Za0, Za1, Za2, Za3);
                radix4_tw<1>(z2, base, gb, Zb0, Zb1, Zb2, Zb3);
            }
        }
        __syncthreads();
        if (tid < MDIM*4) {                          // ct68 stage 2, in place
            int row = tid >> 2, k1 = tid & 3;
            int base = row*RSC2 + 17*k1;
            dft17_sink<1>(z2, base, 1, [&](int k2, float re, float im) {
                z2[base + k2] = make_float2(re, im);
            });
        }
        __syncthreads();
        // Store: re -> col 4m+v-8, im -> col 4m+v-6. Strength-reduced walk.
        {
            int m  = 2 + (tid & 63);          // [2,66)
            int y1 = 4 + (tid >> 6);          // [4,20); +16/iter -> [4,132)
            int a  = slot136(y1)*RSC2 + slot68(m);
            float* rowp = op + (size_t)(2*y1 + u - 8)*256 + 4*m + v - 8;
#pragma unroll
            for (int it = 0; it < 8; ++it) {
                float2 w = z2[a];
                rowp[0] = w.x;                // y2' = 2m
                rowp[2] = w.y;                // y2' = 2m+1
                a += 2*RSC2;                  // slot136(y1+16) = slot136(y1) + 2
                rowp += 32*256;
            }
        }
        __syncthreads();                      // z2 reads done before next S writes
    }
}

// ---------- Per-channel multiplier precompute (f32, R table in LDS) ----------
// Output: Abuf[(c*4 + u*2 + v)*PLANE_HALF + e] = M_{u,v}  (float2)
__global__ void prep_kernel(const float* __restrict__ weight,
                            const float* __restrict__ bias,
                            float2* __restrict__ Abuf)
{
    __shared__ float tabc[272], tabs[272];    // exp(-2*pi*i*t/272)
    __shared__ float Rs[69*5*4];              // (g2*5+a)*4 + {R0r,R0i,R1r,R1i}
    for (int t = threadIdx.x; t < 272; t += blockDim.x) {
        float s, c; sincosf(-2.0f*(float)PI_D*(float)t/272.0f, &s, &c);
        tabc[t] = c; tabs[t] = s;
    }
    const int c     = blockIdx.x >> 3;
    const int chunk = blockIdx.x & 7;
    const float* wp = weight + c*25;
    const float r = 1.0f/(1.0f + expf(9.0f - bias[c])) + 1e-5f;
    __syncthreads();
    for (int it = threadIdx.x; it < 69*5; it += blockDim.x) {
        int g2 = it / 5, a = it - 5*g2;
        float c2 = tabc[g2], s2 = tabs[g2];
        float e2r[5], e2i[5];
        e2r[2]=1.0f; e2i[2]=0.0f; e2r[3]=c2; e2i[3]=s2;
        e2r[4]=c2*c2-s2*s2; e2i[4]=2.0f*c2*s2;
        e2r[1]=c2; e2i[1]=-s2; e2r[0]=e2r[4]; e2i[0]=-e2i[4];
        float w0=wp[a*5+0], w1=wp[a*5+1], w2=wp[a*5+2], w3=wp[a*5+3], w4=wp[a*5+4];
        float Rer = w0*e2r[0] + w2*e2r[2] + w4*e2r[4];
        float Rei = w0*e2i[0] + w2*e2i[2] + w4*e2i[4];
        float Ror = w1*e2r[1] + w3*e2r[3];
        float Roi = w1*e2i[1] + w3*e2i[3];
        Rs[it*4+0] = Rer + Ror;  Rs[it*4+1] = Rei + Roi;   // R0
        Rs[it*4+2] = Rer - Ror;  Rs[it*4+3] = Rei - Roi;   // R1
    }
    __syncthreads();

    const int e_lo = chunk * 1173;           // 8*1173 == PLANE_HALF
    const int e_hi = e_lo + 1173;
    int e  = e_lo + (int)threadIdx.x;
    int g1 = e / HC, g2 = e - (e/HC)*HC;
    for (; e < e_hi; e += blockDim.x) {
        float c1 = tabc[g1], s1 = tabs[g1];
        float e1r[5], e1i[5];
        e1r[2]=1.0f; e1i[2]=0.0f; e1r[3]=c1; e1i[3]=s1;
        e1r[4]=c1*c1-s1*s1; e1i[4]=2.0f*c1*s1;
        e1r[1]=c1; e1i[1]=-s1; e1r[0]=e1r[4]; e1i[0]=-e1i[4];

        float FBr[2][2], FBi[2][2];
#pragma unroll
        for (int b1 = 0; b1 < 2; b1++) {
            float Per=0.f, Pei=0.f, Por=0.f, Poi=0.f;
#pragma unroll
            for (int a = 0; a < 5; a++) {
                float Rr = Rs[(g2*5+a)*4 + 2*b1];
                float Ri = Rs[(g2*5+a)*4 + 2*b1 + 1];
                float tr = e1r[a]*Rr - e1i[a]*Ri;
                float ti = e1r[a]*Ri + e1i[a]*Rr;
                if (a & 1) { Por += tr; Poi += ti; } else { Per += tr; Pei += ti; }
            }
            FBr[0][b1] = Per + Por;  FBi[0][b1] = Pei + Poi;
            FBr[1][b1] = Per - Por;  FBi[1][b1] = Pei - Poi;
        }
        float c2 = tabc[g2], s2 = tabs[g2];
        float ur[2]={1.0f+c1, 1.0f-c1}, ui[2]={s1, -s1};
        float vr[2]={1.0f+c2, 1.0f-c2}, vi[2]={s2, -s2};
        float Br_[2][2], Bi_[2][2];
#pragma unroll
        for (int a1 = 0; a1 < 2; a1++)
#pragma unroll
            for (int b1 = 0; b1 < 2; b1++) {
                Br_[a1][b1] = ur[a1]*vr[b1] - ui[a1]*vi[b1];
                Bi_[a1][b1] = ur[a1]*vi[b1] + ui[a1]*vr[b1];
            }
        float invW=0.f, Qr=0.f, Qi=0.f;
#pragma unroll
        for (int a1 = 0; a1 < 2; a1++)
#pragma unroll
            for (int b1 = 0; b1 < 2; b1++) {
                invW += FBr[a1][b1]*FBr[a1][b1] + FBi[a1][b1]*FBi[a1][b1];
                Qr += FBr[a1][b1]*Br_[a1][b1] - FBi[a1][b1]*Bi_[a1][b1];
                Qi += FBr[a1][b1]*Bi_[a1][b1] + FBi[a1][b1]*Br_[a1][b1];
            }
        invW *= 0.25f; Qr *= 0.25f; Qi *= 0.25f;
        float den = 1.0f/(invW + r);
        float Sr = (1.0f - Qr)*den, Si = -Qi*den;
        float Mr[2][2], Mi[2][2];
#pragma unroll
        for (int a1 = 0; a1 < 2; a1++)
#pragma unroll
            for (int b1 = 0; b1 < 2; b1++) {
                Mr[a1][b1] = Br_[a1][b1] + FBr[a1][b1]*Sr + FBi[a1][b1]*Si;
                Mi[a1][b1] = Bi_[a1][b1] + FBr[a1][b1]*Si - FBi[a1][b1]*Sr;
            }
        const float scale = 1.0f/73984.0f;   // 1/272^2 ifft normalization
#pragma unroll
        for (int uu = 0; uu < 2; uu++)
#pragma unroll
            for (int vv = 0; vv < 2; vv++) {
                float sr=0.f, si=0.f;
#pragma unroll
                for (int a1 = 0; a1 < 2; a1++)
#pragma unroll
                    for (int b1 = 0; b1 < 2; b1++) {
                        if ((a1*uu + b1*vv) & 1) { sr -= Mr[a1][b1]; si -= Mi[a1][b1]; }
                        else                     { sr += Mr[a1][b1]; si += Mi[a1][b1]; }
                    }
                int t = g1*uu + g2*vv;                 // <= 203 < 272
                float pc = tabc[t], ps = -tabs[t];     // exp(+i*pi*t/136)
                Abuf[((size_t)(c*4 + uu*2 + vv))*PLANE_HALF + e] =
                    make_float2((pc*sr - ps*si)*scale, (pc*si + ps*sr)*scale);
            }
        g1 += 3; g2 += 49; if (g2 >= HC) { g2 -= HC; g1++; }   // e += 256
    }
}

extern "C" void kernel_launch(void* const* d_in, const int* in_sizes, int n_in,
                              void* d_out, int out_size, void* d_ws, size_t ws_size,
                              hipStream_t stream)
{
    const float* x      = (const float*)d_in[0];
    const float* weight = (const float*)d_in[1];
    const float* bias   = (const float*)d_in[2];
    float* out = (float*)d_out;

    float2* Abuf = (float2*)d_ws;     // 256 * 9384 * 8B = 19.2 MB

    (void)hipFuncSetAttribute((const void*)conv_kernel,
                              hipFuncAttributeMaxDynamicSharedMemorySize,
                              (int)LDS_BYTES);

    prep_kernel<<<512, 256, 0, stream>>>(weight, bias, Abuf);
    conv_kernel<<<NPLANES, 1024, LDS_BYTES, stream>>>(x, Abuf, out);
}

// Round 15
// 151.668 us; speedup vs baseline: 1.2319x; 1.2319x over previous
//
#include <hip/hip_runtime.h>
#include <math.h>

// Converse2D on gfx950 — spectral restructuring (R17):
//   out(2y+u, 2x+v) plane = ifft136( A_uv[g] * Xhat[g] ), per (n,c,u,v)
//   Xhat = rfft136x136(wrap_pad(x)); A_uv = per-channel multiplier (Hermitian).
// R17 = R16 with the launch-bounds bug fixed. R16's regression was fully
//   explained by __launch_bounds__(1024,8) forcing VGPR=32 -> Xreg spill
//   (FETCH 18->82MB, WRITE 65->168MB). Its occupancy mechanism WORKED
//   (37->43.5% even while spilling; 79.4KB LDS co-locates 2 WGs/CU).
//   Fix: __launch_bounds__(1024,4) -> compiler's natural VGPR=64; at 64 VGPR
//   8 waves/SIMD fit the 512-reg file, so 2 WGs/CU is reachable.
//   Tripwires: VGPR must be 64, WRITE ~65.5MB; else revert to R15.

#define MDIM 136
#define RSC2 73             // float2 plane row stride (69 data + 4 pad/table cols)
#define HC   69             // stored Hermitian half columns (0..68)
#define PLANE_HALF (MDIM*HC)   // 9384 per plane
#define NPLANES 256         // N*C
#define LDS_BYTES (MDIM*RSC2*8)   // 79,424 B -> 2 WGs/CU
#define PI_D 3.14159265358979323846
#define NTH 1024

__device__ __forceinline__ int slot136(int k) { return 17*(k & 7) + (k >> 3); }
__device__ __forceinline__ int slot68(int k)  { return 17*(k & 3) + (k >> 2); }

// ---------- twiddle tables embedded in plane pad columns ----------
__device__ __forceinline__ float2 LUTI(const float2* z, int t)  // exp(+2pi i t/136)
{ return z[t*RSC2 + 69]; }
__device__ __forceinline__ float2 T136(const float2* z, int i)  // w136^(k1*n2), inv dir
{ return z[i*RSC2 + 70]; }
__device__ __forceinline__ float2 T68v(const float2* z, int i)  // w68^((j+1)*n2), inv dir
{ return z[i*RSC2 + 71]; }

// ---------- symmetric 17-point DFT (float2), strided, sink outputs ----------
template<int DIR, class F>
__device__ __forceinline__ void dft17_sink(float2* z, int base, int stride, F f)
{
    constexpr float C17[9] = {1.f, 0.93247223f, 0.73900892f, 0.44573836f,
                              0.09226836f, -0.27366299f, -0.60263464f,
                              -0.85021714f, -0.98297310f};
    constexpr float S17[9] = {0.f, 0.36124167f, 0.67369564f, 0.89516329f,
                              0.99573418f, 0.96182564f, 0.79801723f,
                              0.52643216f, 0.18374952f};
    constexpr float d = (DIR > 0) ? 1.f : -1.f;
    float xr[17], xi[17];
#pragma unroll
    for (int n = 0; n < 17; n++) {
        float2 v = z[base + n*stride];
        xr[n] = v.x; xi[n] = v.y;
    }
    float ar[8], ai[8], br[8], bi[8];
#pragma unroll
    for (int n = 1; n <= 8; n++) {
        ar[n-1] = xr[n] + xr[17-n];  ai[n-1] = xi[n] + xi[17-n];
        br[n-1] = xr[n] - xr[17-n];  bi[n-1] = xi[n] - xi[17-n];
    }
    float s0r = xr[0], s0i = xi[0];
#pragma unroll
    for (int n = 0; n < 8; n++) { s0r += ar[n]; s0i += ai[n]; }
    f(0, s0r, s0i);
#pragma unroll
    for (int k = 1; k <= 8; k++) {
        float Pr = xr[0], Pi = xi[0], Qr = 0.f, Qi = 0.f;
#pragma unroll
        for (int n = 1; n <= 8; n++) {
            int m = (k*n) % 17;
            float cc = (m <= 8) ? C17[m] : C17[17-m];
            float ss = (m <= 8) ? S17[m] : -S17[17-m];
            Pr = fmaf(ar[n-1], cc, Pr);
            Pi = fmaf(ai[n-1], cc, Pi);
            Qr = fmaf(br[n-1], ss, Qr);
            Qi = fmaf(bi[n-1], ss, Qi);
        }
        f(k,    Pr - d*Qi, Pi + d*Qr);
        f(17-k, Pr + d*Qi, Pi - d*Qr);
    }
}

// ---------- radix-4 + embedded-table twiddle; writes col-slots 17j + n2 ----------
template<int DIR>
__device__ __forceinline__ void radix4_tw(float2* z, int base, int n2,
                                          float2 Z0, float2 Z1, float2 Z2, float2 Z3)
{
    constexpr float d = (DIR > 0) ? 1.0f : -1.0f;
    float t0r = Z0.x+Z2.x, t0i = Z0.y+Z2.y;
    float t1r = Z0.x-Z2.x, t1i = Z0.y-Z2.y;
    float t2r = Z1.x+Z3.x, t2i = Z1.y+Z3.y;
    float t3r = Z1.x-Z3.x, t3i = Z1.y-Z3.y;
    float X0r = t0r+t2r,     X0i = t0i+t2i;
    float X2r = t0r-t2r,     X2i = t0i-t2i;
    float X1r = t1r - d*t3i, X1i = t1i + d*t3r;
    float X3r = t1r + d*t3i, X3i = t1i - d*t3r;
    z[base + n2] = make_float2(X0r, X0i);
    float2 w1 = T68v(z, n2), w2 = T68v(z, 17 + n2), w3 = T68v(z, 34 + n2);
    if (DIR < 0) { w1.y = -w1.y; w2.y = -w2.y; w3.y = -w3.y; }
    z[base + 17 + n2] = make_float2(X1r*w1.x - X1i*w1.y, X1r*w1.y + X1i*w1.x);
    z[base + 34 + n2] = make_float2(X2r*w2.x - X2i*w2.y, X2r*w2.y + X2i*w2.x);
    z[base + 51 + n2] = make_float2(X3r*w3.x - X3i*w3.y, X3r*w3.y + X3i*w3.x);
}

// ---------- 136-pt CT stage 1 (radix-8 + embedded-table twiddle) ----------
template<int DIR>
__device__ __forceinline__ void fft136_s1_body(float2* z, int c, int n2)
{
    constexpr float d = (DIR > 0) ? 1.0f : -1.0f;
    constexpr float C707 = 0.70710678118654752f;
    float xr[8], xi[8];
#pragma unroll
    for (int n1 = 0; n1 < 8; n1++) {
        float2 v = z[(17*n1 + n2)*RSC2 + c];
        xr[n1] = v.x; xi[n1] = v.y;
    }
    float e0r = xr[0]+xr[4], e0i = xi[0]+xi[4];
    float e1r = xr[0]-xr[4], e1i = xi[0]-xi[4];
    float o0r = xr[2]+xr[6], o0i = xi[2]+xi[6];
    float o1r = xr[2]-xr[6], o1i = xi[2]-xi[6];
    float E0r = e0r+o0r, E0i = e0i+o0i;
    float E2r = e0r-o0r, E2i = e0i-o0i;
    float E1r = e1r - d*o1i, E1i = e1i + d*o1r;
    float E3r = e1r + d*o1i, E3i = e1i - d*o1r;
    float f0r = xr[1]+xr[5], f0i = xi[1]+xi[5];
    float f1r = xr[1]-xr[5], f1i = xi[1]-xi[5];
    float h0r = xr[3]+xr[7], h0i = xi[3]+xi[7];
    float h1r = xr[3]-xr[7], h1i = xi[3]-xi[7];
    float O0r = f0r+h0r, O0i = f0i+h0i;
    float O2r = f0r-h0r, O2i = f0i-h0i;
    float O1r = f1r - d*h1i, O1i = f1i + d*h1r;
    float O3r = f1r + d*h1i, O3i = f1i - d*h1r;
    float t1r =  C707*(O1r - d*O1i), t1i = C707*(O1i + d*O1r);
    float t2r = -d*O2i,              t2i = d*O2r;
    float t3r = -C707*(O3r + d*O3i), t3i = C707*(d*O3r - O3i);
    float Xr[8], Xi[8];
    Xr[0]=E0r+O0r; Xi[0]=E0i+O0i;  Xr[4]=E0r-O0r; Xi[4]=E0i-O0i;
    Xr[1]=E1r+t1r; Xi[1]=E1i+t1i;  Xr[5]=E1r-t1r; Xi[5]=E1i-t1i;
    Xr[2]=E2r+t2r; Xi[2]=E2i+t2i;  Xr[6]=E2r-t2r; Xi[6]=E2i-t2i;
    Xr[3]=E3r+t3r; Xi[3]=E3i+t3i;  Xr[7]=E3r-t3r; Xi[7]=E3i-t3i;
    z[n2*RSC2 + c] = make_float2(Xr[0], Xi[0]);
#pragma unroll
    for (int k1 = 1; k1 < 8; k1++) {
        float2 w = T136(z, (k1-1)*17 + n2);
        if (DIR < 0) w.y = -w.y;
        z[(17*k1 + n2)*RSC2 + c] = make_float2(Xr[k1]*w.x - Xi[k1]*w.y,
                                               Xr[k1]*w.y + Xi[k1]*w.x);
    }
}

// c2r pack: Zf[j] from a=T[j], b=T[68-j], w=lut[j] (+1 dir LUT).
__device__ __forceinline__ float2 c2r_pack(float2 a, float2 b, float2 w)
{
    float Sr = a.x + b.x, Si = a.y - b.y;
    float Dr = a.x - b.x, Di = a.y + b.y;
    float Or = w.x*Dr - w.y*Di, Oi = w.x*Di + w.y*Dr;
    return make_float2(Sr - Oi, Si + Or);
}

// ---------- Fused forward + inverse: one WG per (n,c) plane (256 WGs) ----------
__global__ __launch_bounds__(1024, 4) void conv_kernel(const float* __restrict__ x,
                                                       const float2* __restrict__ Abuf,
                                                       float* __restrict__ out)
{
    extern __shared__ float2 z2[];           // [136][73]: cols 0..68 data, 69..71 tables
    const int tid = threadIdx.x;
    const int nc  = blockIdx.x;              // n*64 + c
    const int c   = nc & 63;

    if (tid < MDIM) {
        float s, cc; sincosf(2.0f*(float)PI_D*(float)tid/136.0f, &s, &cc);
        z2[tid*RSC2 + 69] = make_float2(cc, s);                 // lutI
    } else if (tid < MDIM + 119) {
        int it = tid - MDIM;
        int k1 = it/17 + 1, n2 = it - (it/17)*17;
        float s, cc; sincosf((float)(PI_D/68.0)*(float)(k1*n2), &s, &cc);
        z2[it*RSC2 + 70] = make_float2(cc, s);                  // tI136
    } else if (tid < MDIM + 119 + 51) {
        int it = tid - MDIM - 119;
        int j = it/17, n2 = it - 17*j;
        float s, cc; sincosf((float)(PI_D/34.0)*(float)((j+1)*n2), &s, &cc);
        z2[it*RSC2 + 71] = make_float2(cc, s);                  // tI68
    }
    // ---------------- forward ----------------
    const float* xp = x + (size_t)nc * (128*128);
    {   // packed-row load: z2[i][n] = xp(i,2n) + i*xp(i,2n+1), wrap pad by 4
        int i = tid / 68, n = tid - (tid/68)*68;
        for (int e = tid; e < MDIM*68; e += NTH) {
            int si = (i + 124) & 127;
            int j0 = (2*n + 124) & 127;              // always even, pair never wraps
            z2[i*RSC2 + n] = *reinterpret_cast<const float2*>(xp + si*128 + j0);
            i += 15; n += 4; if (n >= 68) { n -= 68; i++; }
        }
    }
    __syncthreads();
    {   // rows stage 1 (radix-4)
        int row = tid / 17;
        int n2  = tid - row*17;
        for (int e = tid; e < MDIM*17; e += NTH) {
            int base = row*RSC2;
            float2 Z0 = z2[base + n2];
            float2 Z1 = z2[base + 17 + n2];
            float2 Z2 = z2[base + 34 + n2];
            float2 Z3 = z2[base + 51 + n2];
            radix4_tw<-1>(z2, base, n2, Z0, Z1, Z2, Z3);
            row += 60; n2 += 4; if (n2 >= 17) { n2 -= 17; row++; }
        }
    }
    __syncthreads();
    if (tid < MDIM*4) {                              // rows stage 2: Z[k] at slot68(k)
        int row = tid >> 2, k1 = tid & 3;
        int base = row*RSC2 + 17*k1;
        dft17_sink<-1>(z2, base, 1, [&](int k2, float re, float im) {
            z2[base + k2] = make_float2(re, im);
        });
    }
    __syncthreads();
    {   // r2c unpack: item k handles (k, 68-k), in-place at slots
        int row = tid / 35, k = tid - (tid/35)*35;
        for (int e = tid; e < MDIM*35; e += NTH) {
            int base = row*RSC2;
            int sa = slot68(k);
            float2 Za = z2[base+sa];
            float Zar = Za.x, Zai = Za.y;
            float Zbr, Zbi; int sb;
            if (k == 0) { Zbr = Zar; Zbi = Zai; sb = 68; }  // Z[68]==Z[0]; X[68]->col 68
            else {
                int kk = 68-k; sb = slot68(kk);
                float2 Zb = z2[base+sb]; Zbr = Zb.x; Zbi = Zb.y;
            }
            float2 w = LUTI(z2, k);                         // conj -> fwd w136^k
            float wc = w.x, ws = -w.y;
            float Er = 0.5f*(Zar + Zbr), Ei = 0.5f*(Zai - Zbi);
            float Dr = 0.5f*(Zar - Zbr), Di = 0.5f*(Zai + Zbi);
            float Tr = wc*Dr - ws*Di, Ti = wc*Di + ws*Dr;   // w^k * D
            z2[base+sa] = make_float2(Er + Ti, Ei - Tr);    // X[k] = E - i*(w^k D)
            float E2r = Er,  E2i = -Ei;
            float D2r = -Dr, D2i = Di;
            float w2c = -wc, w2s = ws;                      // w136^(68-k) = -conj(w^k)
            float T2r = w2c*D2r - w2s*D2i, T2i = w2c*D2i + w2s*D2r;
            z2[base+sb] = make_float2(E2r + T2i, E2i - T2r); // X[68-k]
            row += 29; k += 9; if (k >= 35) { k -= 35; row++; }
        }
    }
    __syncthreads();
    for (int e = tid; e < HC*17; e += NTH) {         // columns stage 1 (69 cols)
        int cc = (e*241) >> 12;                      // e/17, e <= 1172
        int n2 = e - cc*17;
        fft136_s1_body<-1>(z2, cc, n2);
    }
    __syncthreads();
    if (tid < HC*8) {                                // columns stage 2, in place
        int cc = tid >> 3, k1 = tid & 7;
        int base = 17*k1*RSC2 + cc;
        dft17_sink<-1>(z2, base, RSC2, [&](int k2, float re, float im) {
            z2[base + k2*RSC2] = make_float2(re, im);
        });
    }
    __syncthreads();
    // ---------------- capture Xhat to registers ----------------
    float2 Xreg[10];
    {
        int g1 = tid / HC, g2 = tid - (tid/HC)*HC;
#pragma unroll
        for (int k = 0; k < 10; k++) {
            if (k < 9 || tid < PLANE_HALF - 9*NTH) {     // tail: 168 threads
                int cq = (g2 == 68) ? 68 : slot68(g2);
                Xreg[k] = z2[slot136(g1)*RSC2 + cq];
            }
            g1 += 14; g2 += 58; if (g2 >= HC) { g2 -= HC; g1++; }
        }
    }
    __syncthreads();
    // ---------------- inverse, four (u,v) iterations ----------------
    float* op = out + (size_t)nc * (256*256);
#pragma unroll 1
    for (int uv = 0; uv < 4; uv++) {
        const int u = uv >> 1, v = uv & 1;
        const float2* Ap = Abuf + (size_t)(c*4 + u*2 + v) * PLANE_HALF;
        {   // S = A_uv * Xhat, natural [g1][g2]
            int g1 = tid / HC, g2 = tid - (tid/HC)*HC;
#pragma unroll
            for (int k = 0; k < 10; k++) {
                if (k < 9 || tid < PLANE_HALF - 9*NTH) {
                    float2 xv = Xreg[k];
                    float2 av = Ap[tid + k*NTH];
                    z2[g1*RSC2 + g2] = make_float2(av.x*xv.x - av.y*xv.y,
                                                   av.x*xv.y + av.y*xv.x);
                }
                g1 += 14; g2 += 58; if (g2 >= HC) { g2 -= HC; g1++; }
            }
        }
        __syncthreads();
        for (int e = tid; e < HC*17; e += NTH) {     // columns stage 1
            int cc = (e*241) >> 12;
            int n2 = e - cc*17;
            fft136_s1_body<1>(z2, cc, n2);
        }
        __syncthreads();
        if (tid < HC*8) {                            // columns stage 2 (rows->slot136)
            int cc = tid >> 3, k1 = tid & 7;
            int base = 17*k1*RSC2 + cc;
            dft17_sink<1>(z2, base, RSC2, [&](int k2, float re, float im) {
                z2[base + k2*RSC2] = make_float2(re, im);
            });
        }
        __syncthreads();
        // Fused c2r pack + ct68 stage 1 (rows): 136*9 = 1224 items.
        for (int it = tid; it < MDIM*9; it += NTH) {
            int row = (it*7282) >> 16;                // it/9, it <= 1223
            int g   = it - row*9;
            int base = row*RSC2;
            if (g == 0) {
                float2 T0  = z2[base],    T17 = z2[base+17], T34 = z2[base+34],
                       T51 = z2[base+51], T68 = z2[base+68];
                float2 Z0 = c2r_pack(T0,  T68, LUTI(z2, 0));
                float2 Z1 = c2r_pack(T17, T51, LUTI(z2, 17));
                float2 Z2 = c2r_pack(T34, T34, LUTI(z2, 34));
                float2 Z3 = c2r_pack(T51, T17, LUTI(z2, 51));
                radix4_tw<1>(z2, base, 0, Z0, Z1, Z2, Z3);
            } else {
                int gb = 17 - g;
                float2 Ta0 = z2[base+g],    Ta1 = z2[base+g+17],
                       Ta2 = z2[base+g+34], Ta3 = z2[base+g+51];
                float2 Tb0 = z2[base+gb],    Tb1 = z2[base+gb+17],
                       Tb2 = z2[base+gb+34], Tb3 = z2[base+gb+51];
                // partner of (g+17*n1) is (gb+17*(3-n1)), and vice versa
                float2 Za0 = c2r_pack(Ta0, Tb3, LUTI(z2, g));
                float2 Za1 = c2r_pack(Ta1, Tb2, LUTI(z2, g+17));
                float2 Za2 = c2r_pack(Ta2, Tb1, LUTI(z2, g+34));
                float2 Za3 = c2r_pack(Ta3, Tb0, LUTI(z2, g+51));
                float2 Zb0 = c2r_pack(Tb0, Ta3, LUTI(z2, gb));
                float2 Zb1 = c2r_pack(Tb1, Ta2, LUTI(z2, gb+17));
                float2 Zb2 = c2r_pack(Tb2, Ta1, LUTI(z2, gb+34));
                float2 Zb3 = c2r_pack(Tb3, Ta0, LUTI(z2, gb+51));
                radix4_tw<1>(z2, base, g,  Za0, Za1, Za2, Za3);
                radix4_tw<1>(z2, base, gb, Zb0, Zb1, Zb2, Zb3);
            }
        }
        __syncthreads();
        if (tid < MDIM*4) {                          // ct68 stage 2, in place
            int row = tid >> 2, k1 = tid & 3;
            int base = row*RSC2 + 17*k1;
            dft17_sink<1>(z2, base, 1, [&](int k2, float re, float im) {
                z2[base + k2] = make_float2(re, im);
            });
        }
        __syncthreads();
        // Store: re -> col 4m+v-8, im -> col 4m+v-6. Strength-reduced walk.
        {
            int m  = 2 + (tid & 63);          // [2,66)
            int y1 = 4 + (tid >> 6);          // [4,20); +16/iter -> [4,132)
            int a  = slot136(y1)*RSC2 + slot68(m);
            float* rowp = op + (size_t)(2*y1 + u - 8)*256 + 4*m + v - 8;
#pragma unroll
            for (int it = 0; it < 8; ++it) {
                float2 w = z2[a];
                rowp[0] = w.x;                // y2' = 2m
                rowp[2] = w.y;                // y2' = 2m+1
                a += 2*RSC2;                  // slot136(y1+16) = slot136(y1) + 2
                rowp += 32*256;
            }
        }
        __syncthreads();                      // z2 reads done before next S writes
    }
}

// ---------- Per-channel multiplier precompute (f32, R table in LDS) ----------
// Output: Abuf[(c*4 + u*2 + v)*PLANE_HALF + e] = M_{u,v}  (float2)
__global__ void prep_kernel(const float* __restrict__ weight,
                            const float* __restrict__ bias,
                            float2* __restrict__ Abuf)
{
    __shared__ float tabc[272], tabs[272];    // exp(-2*pi*i*t/272)
    __shared__ float Rs[69*5*4];              // (g2*5+a)*4 + {R0r,R0i,R1r,R1i}
    for (int t = threadIdx.x; t < 272; t += blockDim.x) {
        float s, c; sincosf(-2.0f*(float)PI_D*(float)t/272.0f, &s, &c);
        tabc[t] = c; tabs[t] = s;
    }
    const int c     = blockIdx.x >> 3;
    const int chunk = blockIdx.x & 7;
    const float* wp = weight + c*25;
    const float r = 1.0f/(1.0f + expf(9.0f - bias[c])) + 1e-5f;
    __syncthreads();
    for (int it = threadIdx.x; it < 69*5; it += blockDim.x) {
        int g2 = it / 5, a = it - 5*g2;
        float c2 = tabc[g2], s2 = tabs[g2];
        float e2r[5], e2i[5];
        e2r[2]=1.0f; e2i[2]=0.0f; e2r[3]=c2; e2i[3]=s2;
        e2r[4]=c2*c2-s2*s2; e2i[4]=2.0f*c2*s2;
        e2r[1]=c2; e2i[1]=-s2; e2r[0]=e2r[4]; e2i[0]=-e2i[4];
        float w0=wp[a*5+0], w1=wp[a*5+1], w2=wp[a*5+2], w3=wp[a*5+3], w4=wp[a*5+4];
        float Rer = w0*e2r[0] + w2*e2r[2] + w4*e2r[4];
        float Rei = w0*e2i[0] + w2*e2i[2] + w4*e2i[4];
        float Ror = w1*e2r[1] + w3*e2r[3];
        float Roi = w1*e2i[1] + w3*e2i[3];
        Rs[it*4+0] = Rer + Ror;  Rs[it*4+1] = Rei + Roi;   // R0
        Rs[it*4+2] = Rer - Ror;  Rs[it*4+3] = Rei - Roi;   // R1
    }
    __syncthreads();

    const int e_lo = chunk * 1173;           // 8*1173 == PLANE_HALF
    const int e_hi = e_lo + 1173;
    int e  = e_lo + (int)threadIdx.x;
    int g1 = e / HC, g2 = e - (e/HC)*HC;
    for (; e < e_hi; e += blockDim.x) {
        float c1 = tabc[g1], s1 = tabs[g1];
        float e1r[5], e1i[5];
        e1r[2]=1.0f; e1i[2]=0.0f; e1r[3]=c1; e1i[3]=s1;
        e1r[4]=c1*c1-s1*s1; e1i[4]=2.0f*c1*s1;
        e1r[1]=c1; e1i[1]=-s1; e1r[0]=e1r[4]; e1i[0]=-e1i[4];

        float FBr[2][2], FBi[2][2];
#pragma unroll
        for (int b1 = 0; b1 < 2; b1++) {
            float Per=0.f, Pei=0.f, Por=0.f, Poi=0.f;
#pragma unroll
            for (int a = 0; a < 5; a++) {
                float Rr = Rs[(g2*5+a)*4 + 2*b1];
                float Ri = Rs[(g2*5+a)*4 + 2*b1 + 1];
                float tr = e1r[a]*Rr - e1i[a]*Ri;
                float ti = e1r[a]*Ri + e1i[a]*Rr;
                if (a & 1) { Por += tr; Poi += ti; } else { Per += tr; Pei += ti; }
            }
            FBr[0][b1] = Per + Por;  FBi[0][b1] = Pei + Poi;
            FBr[1][b1] = Per - Por;  FBi[1][b1] = Pei - Poi;
        }
        float c2 = tabc[g2], s2 = tabs[g2];
        float ur[2]={1.0f+c1, 1.0f-c1}, ui[2]={s1, -s1};
        float vr[2]={1.0f+c2, 1.0f-c2}, vi[2]={s2, -s2};
        float Br_[2][2], Bi_[2][2];
#pragma unroll
        for (int a1 = 0; a1 < 2; a1++)
#pragma unroll
            for (int b1 = 0; b1 < 2; b1++) {
                Br_[a1][b1] = ur[a1]*vr[b1] - ui[a1]*vi[b1];
                Bi_[a1][b1] = ur[a1]*vi[b1] + ui[a1]*vr[b1];
            }
        float invW=0.f, Qr=0.f, Qi=0.f;
#pragma unroll
        for (int a1 = 0; a1 < 2; a1++)
#pragma unroll
            for (int b1 = 0; b1 < 2; b1++) {
                invW += FBr[a1][b1]*FBr[a1][b1] + FBi[a1][b1]*FBi[a1][b1];
                Qr += FBr[a1][b1]*Br_[a1][b1] - FBi[a1][b1]*Bi_[a1][b1];
                Qi += FBr[a1][b1]*Bi_[a1][b1] + FBi[a1][b1]*Br_[a1][b1];
            }
        invW *= 0.25f; Qr *= 0.25f; Qi *= 0.25f;
        float den = 1.0f/(invW + r);
        float Sr = (1.0f - Qr)*den, Si = -Qi*den;
        float Mr[2][2], Mi[2][2];
#pragma unroll
        for (int a1 = 0; a1 < 2; a1++)
#pragma unroll
            for (int b1 = 0; b1 < 2; b1++) {
                Mr[a1][b1] = Br_[a1][b1] + FBr[a1][b1]*Sr + FBi[a1][b1]*Si;
                Mi[a1][b1] = Bi_[a1][b1] + FBr[a1][b1]*Si - FBi[a1][b1]*Sr;
            }
        const float scale = 1.0f/73984.0f;   // 1/272^2 ifft normalization
#pragma unroll
        for (int uu = 0; uu < 2; uu++)
#pragma unroll
            for (int vv = 0; vv < 2; vv++) {
                float sr=0.f, si=0.f;
#pragma unroll
                for (int a1 = 0; a1 < 2; a1++)
#pragma unroll
                    for (int b1 = 0; b1 < 2; b1++) {
                        if ((a1*uu + b1*vv) & 1) { sr -= Mr[a1][b1]; si -= Mi[a1][b1]; }
                        else                     { sr += Mr[a1][b1]; si += Mi[a1][b1]; }
                    }
                int t = g1*uu + g2*vv;                 // <= 203 < 272
                float pc = tabc[t], ps = -tabs[t];     // exp(+i*pi*t/136)
                Abuf[((size_t)(c*4 + uu*2 + vv))*PLANE_HALF + e] =
                    make_float2((pc*sr - ps*si)*scale, (pc*si + ps*sr)*scale);
            }
        g1 += 3; g2 += 49; if (g2 >= HC) { g2 -= HC; g1++; }   // e += 256
    }
}

extern "C" void kernel_launch(void* const* d_in, const int* in_sizes, int n_in,
                              void* d_out, int out_size, void* d_ws, size_t ws_size,
                              hipStream_t stream)
{
    const float* x      = (const float*)d_in[0];
    const float* weight = (const float*)d_in[1];
    const float* bias   = (const float*)d_in[2];
    float* out = (float*)d_out;

    float2* Abuf = (float2*)d_ws;     // 256 * 9384 * 8B = 19.2 MB

    (void)hipFuncSetAttribute((const void*)conv_kernel,
                              hipFuncAttributeMaxDynamicSharedMemorySize,
                              (int)LDS_BYTES);

    prep_kernel<<<512, 256, 0, stream>>>(weight, bias, Abuf);
    conv_kernel<<<NPLANES, 1024, LDS_BYTES, stream>>>(x, Abuf, out);
}